// Round 15
// baseline (163.794 us; speedup 1.0000x reference)
//
#include <hip/hip_runtime.h>

// VQ codebook via MFMA: z_e (262144,64) f32, embeddings (512,64) f32.
// Outputs (flat f32): z_q_st [N*D], indices-as-float [N], loss [1].
//
// R15: ZERO in-loop barriers. E-fragments read per-lane from global
// (contiguous across lanes -> coalesced dwordx4; 128KB codebook is L2/L1-hot)
// instead of LDS staging -- R14 post-mortem: per-iter __syncthreads (vmcnt
// drain + 4-wave lockstep) left issue utilization at ~20%. LDS now ~2.8KB.
// Flag-rescan INLINED (per-wave ballot -> whole-wave exact f32 scan, same
// lexicographic argmin as R14's vq_fix) -> vq_fix/dl/dl_reduce/memsets/
// atomics all deleted; 3 launches total, fully deterministic.
// MFMA order / bf16 RNE split / ARGMIN logic bitwise = R11-R14 (absmax 0).

typedef short  bf16x8 __attribute__((ext_vector_type(8)));
typedef float  f32x4  __attribute__((ext_vector_type(4)));

static constexpr int N_TOK = 262144;
static constexpr int K     = 512;
static constexpr int D     = 64;
static constexpr float THRESH = 0.02f;
static constexpr int NBLK_A = N_TOK / 128;    // 2048 vq_mfma blocks

// ws layout (bytes)
static constexpr size_t WS_ESQ   = 0;         //  512 f32 (2048 B)
static constexpr size_t WS_BL    = 2048;      // 2048 f32 (8192 B)
static constexpr size_t WS_EFRAG = 10240;     // 65536 u16 (131072 B), 16B-al

// ---- prep: E' = -2E -> bf16 hi/lo A-frags, fused with esq ------------------
__global__ __launch_bounds__(512) void prep_kernel(
    const float* __restrict__ emb, unsigned short* __restrict__ ef,
    float* __restrict__ esq) {
  int idx  = blockIdx.x * 512 + threadIdx.x;   // 32768 = 512 codes * 64 d
  int code = idx >> 6, d = idx & 63;
  float s  = -2.0f * emb[code * 64 + d];
  unsigned u  = __float_as_uint(s);
  unsigned hi = (u + 0x7FFFu + ((u >> 16) & 1u)) >> 16;       // RNE bf16
  float lof   = s - __uint_as_float(hi << 16);
  unsigned v2 = __float_as_uint(lof);
  unsigned lo = (v2 + 0x7FFFu + ((v2 >> 16) & 1u)) >> 16;     // RNE bf16
  int tile = code >> 4, row = code & 15;
  int c = (d >> 5) & 1, g = (d >> 3) & 3, i = d & 7;
  int lane = row + (g << 4);
  size_t base = ((size_t)tile * 256 + (size_t)c * 128) * 8;
  ef[base + (size_t)(0 * 64 + lane) * 8 + i] = (unsigned short)hi;
  ef[base + (size_t)(1 * 64 + lane) * 8 + i] = (unsigned short)lo;
  // esq for this block's 8 codes (rows are L1-hot from the writes above).
  if (threadIdx.x < 8) {
    int k = blockIdx.x * 8 + threadIdx.x;
    const float4* row4 = reinterpret_cast<const float4*>(emb + (size_t)k * D);
    float acc = 0.f;
#pragma unroll
    for (int j = 0; j < 16; ++j) {
      float4 v = row4[j];
      acc = fmaf(v.x, v.x, acc); acc = fmaf(v.y, v.y, acc);
      acc = fmaf(v.z, v.z, acc); acc = fmaf(v.w, v.w, acc);
    }
    esq[k] = acc;
  }
}

// RNE bf16 two-term split of 8 floats -> hi/lo bf16x8.
__device__ __forceinline__ void split8(float4 a, float4 b,
                                       bf16x8& h, bf16x8& lo) {
  float v[8] = {a.x, a.y, a.z, a.w, b.x, b.y, b.z, b.w};
#pragma unroll
  for (int i = 0; i < 8; ++i) {
    unsigned u  = __float_as_uint(v[i]);
    unsigned hi = (u + 0x7FFFu + ((u >> 16) & 1u)) >> 16;
    float lof   = v[i] - __uint_as_float(hi << 16);
    unsigned v2 = __float_as_uint(lof);
    unsigned l2 = (v2 + 0x7FFFu + ((v2 >> 16) & 1u)) >> 16;
    h[i]  = (short)hi;
    lo[i] = (short)l2;
  }
}

#define ARGMIN4(C, BASE, BEST, SECOND, BIDXV)               \
  {                                                         \
    _Pragma("unroll")                                       \
    for (int r = 0; r < 4; ++r) {                           \
      float v = (C)[r];                                     \
      bool lt = v < (BEST);                                 \
      float mn = fminf((SECOND), v);                        \
      (SECOND) = lt ? (BEST) : mn;                          \
      (BIDXV)  = lt ? ((BASE) + r) : (BIDXV);               \
      (BEST)   = lt ? v : (BEST);                           \
    }                                                       \
  }

// ---- kernel A: MFMA distances + inline rescan + fused epilogue -------------
__global__ __launch_bounds__(256) void vq_mfma(
    const float* __restrict__ z_e, const float* __restrict__ emb,
    const unsigned short* __restrict__ efrag, const float* __restrict__ esq_g,
    float* __restrict__ out_zq, float* __restrict__ out_idx,
    float* __restrict__ block_loss) {
  __shared__ float esql[K];                        // 2048 B
  __shared__ int   sIdx[128];
  __shared__ float wsm[4];

  const int t  = threadIdx.x;
  const int l  = t & 63;
  const int w  = t >> 6;
  const int g  = l >> 4, g4 = g << 2;
  const int gtok0 = blockIdx.x * 128;

  esql[t] = esq_g[t];
  esql[t + 256] = esq_g[t + 256];

  // z frags for two token rows, direct from global. RNE split = efrag's.
  bf16x8 zh0A, zl0A, zh1A, zl1A, zh0B, zl0B, zh1B, zl1B;
  {
    const int rowA = gtok0 + w * 32 + (l & 15);
    const float* zp = z_e + (size_t)rowA * D + g * 8;
    float4 q0 = *reinterpret_cast<const float4*>(zp);
    float4 q1 = *reinterpret_cast<const float4*>(zp + 4);
    float4 q2 = *reinterpret_cast<const float4*>(zp + 32);
    float4 q3 = *reinterpret_cast<const float4*>(zp + 36);
    split8(q0, q1, zh0A, zl0A);
    split8(q2, q3, zh1A, zl1A);
    zp += (size_t)16 * D;                          // rowB = rowA + 16
    q0 = *reinterpret_cast<const float4*>(zp);
    q1 = *reinterpret_cast<const float4*>(zp + 4);
    q2 = *reinterpret_cast<const float4*>(zp + 32);
    q3 = *reinterpret_cast<const float4*>(zp + 36);
    split8(q0, q1, zh0B, zl0B);
    split8(q2, q3, zh1B, zl1B);
  }
  __syncthreads();                                 // esql ready (one-time)

  float bestA = 3.402823466e38f, secondA = 3.402823466e38f;
  float bestB = 3.402823466e38f, secondB = 3.402823466e38f;
  int idxA = 0, idxB = 0;

  const bf16x8* EF = reinterpret_cast<const bf16x8*>(efrag);

  for (int tile = 0; tile < 32; ++tile) {
    const bf16x8* EFt = EF + (size_t)tile * 256 + l;  // coalesced across lanes
    f32x4 CA = *reinterpret_cast<const f32x4*>(&esql[tile * 16 + g4]);
    f32x4 CB = CA;
    // k-chunk 0 (E live set kept at 2 frags to stay under 64 VGPR).
    bf16x8 e0h = EFt[0], e0l = EFt[64];
    __builtin_amdgcn_s_setprio(1);
    CA = __builtin_amdgcn_mfma_f32_16x16x32_bf16(e0h, zh0A, CA, 0, 0, 0);
    CB = __builtin_amdgcn_mfma_f32_16x16x32_bf16(e0h, zh0B, CB, 0, 0, 0);
    CA = __builtin_amdgcn_mfma_f32_16x16x32_bf16(e0h, zl0A, CA, 0, 0, 0);
    CB = __builtin_amdgcn_mfma_f32_16x16x32_bf16(e0h, zl0B, CB, 0, 0, 0);
    CA = __builtin_amdgcn_mfma_f32_16x16x32_bf16(e0l, zh0A, CA, 0, 0, 0);
    CB = __builtin_amdgcn_mfma_f32_16x16x32_bf16(e0l, zh0B, CB, 0, 0, 0);
    __builtin_amdgcn_s_setprio(0);
    // k-chunk 1
    bf16x8 e1h = EFt[128], e1l = EFt[192];
    __builtin_amdgcn_s_setprio(1);
    CA = __builtin_amdgcn_mfma_f32_16x16x32_bf16(e1h, zh1A, CA, 0, 0, 0);
    CB = __builtin_amdgcn_mfma_f32_16x16x32_bf16(e1h, zh1B, CB, 0, 0, 0);
    CA = __builtin_amdgcn_mfma_f32_16x16x32_bf16(e1h, zl1A, CA, 0, 0, 0);
    CB = __builtin_amdgcn_mfma_f32_16x16x32_bf16(e1h, zl1B, CB, 0, 0, 0);
    CA = __builtin_amdgcn_mfma_f32_16x16x32_bf16(e1l, zh1A, CA, 0, 0, 0);
    CB = __builtin_amdgcn_mfma_f32_16x16x32_bf16(e1l, zh1B, CB, 0, 0, 0);
    __builtin_amdgcn_s_setprio(0);

    const int base = tile * 16 + g4;               // ascending code order
    ARGMIN4(CA, base, bestA, secondA, idxA)
    ARGMIN4(CB, base, bestB, secondB, idxB)
  }

  // Reduce each group across lanes {l, l^16, l^32, l^48}; ties -> smaller code.
#pragma unroll
  for (int mask = 16; mask <= 32; mask <<= 1) {
    float ob, os; int oi; bool take; float hi2;
    ob = __shfl_xor(bestA, mask); oi = __shfl_xor(idxA, mask);
    os = __shfl_xor(secondA, mask);
    hi2 = fmaxf(bestA, ob);
    secondA = fminf(secondA, fminf(os, hi2));
    take = (ob < bestA) || (ob == bestA && oi < idxA);
    bestA = take ? ob : bestA; idxA = take ? oi : idxA;

    ob = __shfl_xor(bestB, mask); oi = __shfl_xor(idxB, mask);
    os = __shfl_xor(secondB, mask);
    hi2 = fmaxf(bestB, ob);
    secondB = fminf(secondB, fminf(os, hi2));
    take = (ob < bestB) || (ob == bestB && oi < idxB);
    bestB = take ? ob : bestB; idxB = take ? oi : idxB;
  }

  if (l < 16) {
    sIdx[w * 32 + l]      = idxA;
    sIdx[w * 32 + 16 + l] = idxB;
  }

  // Inline exact rescan of flagged tokens (wave-uniform ballot loop).
  {
    bool fA = (l < 16) && ((secondA - bestA) < THRESH);
    bool fB = (l < 16) && ((secondB - bestB) < THRESH);
    unsigned long long ba = __ballot(fA);
    unsigned long long bb = __ballot(fB);
    unsigned mask = (unsigned)((ba & 0xFFFFull) | ((bb & 0xFFFFull) << 16));
    while (mask) {
      const int j = __builtin_ctz(mask);
      mask &= mask - 1;
      const int n = gtok0 + w * 32 + j;
      const float4* zr = reinterpret_cast<const float4*>(z_e + (size_t)n * D);
      float acc[8];
#pragma unroll
      for (int m = 0; m < 8; ++m) acc[m] = 0.f;
#pragma unroll 4
      for (int i = 0; i < 16; ++i) {
        float4 z4 = zr[i];                         // uniform addr broadcast
#pragma unroll
        for (int m = 0; m < 8; ++m) {
          const float4 e4 = *reinterpret_cast<const float4*>(
              emb + (size_t)(l + 64 * m) * D + 4 * i);
          acc[m] = fmaf(z4.x, e4.x, acc[m]);
          acc[m] = fmaf(z4.y, e4.y, acc[m]);
          acc[m] = fmaf(z4.z, e4.z, acc[m]);
          acc[m] = fmaf(z4.w, e4.w, acc[m]);
        }
      }
      float best = 3.402823466e38f; int bid = 0;
#pragma unroll
      for (int m = 0; m < 8; ++m) {
        float s = fmaf(-2.f, acc[m], esq_g[l + 64 * m]);
        if (s < best) { best = s; bid = l + 64 * m; }
      }
#pragma unroll
      for (int mk = 1; mk <= 32; mk <<= 1) {       // lexicographic min
        float ob = __shfl_xor(best, mk);
        int   oi = __shfl_xor(bid, mk);
        bool take = (ob < best) || (ob == best && oi < bid);
        best = take ? ob : best;
        bid  = take ? oi : bid;
      }
      if (l == 0) sIdx[w * 32 + j] = bid;          // patch before epilogue
    }
  }
  __syncthreads();

  // Fused epilogue: 2 threads/token; gather + z_q_st + idx + loss.
  {
    const int tk = t >> 1, h = t & 1;
    const int n = gtok0 + tk;
    const int bi = sIdx[tk];
    const float4* er = reinterpret_cast<const float4*>(emb + (size_t)bi * D);
    const float4* zr = reinterpret_cast<const float4*>(z_e + (size_t)n * D);
    float4* orow = reinterpret_cast<float4*>(out_zq + (size_t)n * D);
    float lsum = 0.f;
#pragma unroll
    for (int j = 0; j < 8; ++j) {
      int i = h * 8 + j;
      float4 Q = er[i], Z = zr[i];
      float dx = Q.x - Z.x, dy = Q.y - Z.y, dz = Q.z - Z.z, dw = Q.w - Z.w;
      float4 st;
      st.x = Z.x + dx; st.y = Z.y + dy; st.z = Z.z + dz; st.w = Z.w + dw;
      orow[i] = st;
      lsum = fmaf(dx, dx, lsum); lsum = fmaf(dy, dy, lsum);
      lsum = fmaf(dz, dz, lsum); lsum = fmaf(dw, dw, lsum);
    }
    if (h == 0) out_idx[n] = (float)bi;
    float s = lsum;
#pragma unroll
    for (int off = 32; off > 0; off >>= 1) s += __shfl_xor(s, off, 64);
    if (l == 0) wsm[w] = s;
  }
  __syncthreads();
  if (t == 0) block_loss[blockIdx.x] = ((wsm[0] + wsm[1]) + wsm[2]) + wsm[3];
}

// ---- finalize loss (deterministic tree) ------------------------------------
__global__ __launch_bounds__(256) void loss_finalize(
    const float* __restrict__ bl, float* __restrict__ out_loss) {
  __shared__ float sm[256];
  const int t = threadIdx.x;
  float s = 0.f;
  for (int i = t; i < NBLK_A; i += 256) s += bl[i];
  sm[t] = s;
  __syncthreads();
#pragma unroll
  for (int off = 128; off > 0; off >>= 1) {
    if (t < off) sm[t] += sm[t + off];
    __syncthreads();
  }
  if (t == 0) out_loss[0] = sm[0] * (1.0f / 16777216.0f);  // /(N*D)
}

extern "C" void kernel_launch(void* const* d_in, const int* in_sizes, int n_in,
                              void* d_out, int out_size, void* d_ws, size_t ws_size,
                              hipStream_t stream) {
  const float* z_e = (const float*)d_in[0];
  const float* emb = (const float*)d_in[1];

  float* out      = (float*)d_out;
  float* out_zq   = out;                          // N*D
  float* out_idx  = out + (size_t)N_TOK * D;      // N
  float* out_loss = out_idx + N_TOK;              // 1

  char* wsb = (char*)d_ws;
  float*          esqp = (float*)(wsb + WS_ESQ);
  float*          bl   = (float*)(wsb + WS_BL);
  unsigned short* ef   = (unsigned short*)(wsb + WS_EFRAG);

  prep_kernel<<<64, 512, 0, stream>>>(emb, ef, esqp);
  vq_mfma<<<NBLK_A, 256, 0, stream>>>(z_e, emb, ef, esqp, out_zq, out_idx, bl);
  loss_finalize<<<1, 256, 0, stream>>>(bl, out_loss);
}

// Round 16
// 144.793 us; speedup vs baseline: 1.1312x; 1.1312x over previous
//
#include <hip/hip_runtime.h>

// VQ codebook via MFMA: z_e (262144,64) f32, embeddings (512,64) f32.
// Outputs (flat f32): z_q_st [N*D], indices-as-float [N], loss [1].
//
// R16 = R14's hot loop (GLDS-staged E-tiles, double-buffered, VGPR 52,
// 108us measured) + R15's 3-launch fusion (inline ballot rescan, fused
// epilogue, no memsets/atomics; tail measured ~4us). R15 lesson: per-lane
// global E-loads -> VGPR 88, occupancy 16% -- LDS staging is required for
// the register budget. R14 lesson: the 6-launch tail cost ~52us.
// MFMA order / bf16 RNE split / ARGMIN logic bitwise = R11-R15 (absmax 0).

typedef short  bf16x8 __attribute__((ext_vector_type(8)));
typedef float  f32x4  __attribute__((ext_vector_type(4)));

static constexpr int N_TOK = 262144;
static constexpr int K     = 512;
static constexpr int D     = 64;
static constexpr float THRESH = 0.02f;
static constexpr int NBLK_A = N_TOK / 128;    // 2048 vq_mfma blocks

// ws layout (bytes)
static constexpr size_t WS_ESQ   = 0;         //  512 f32 (2048 B)
static constexpr size_t WS_BL    = 2048;      // 2048 f32 (8192 B)
static constexpr size_t WS_EFRAG = 10240;     // 65536 u16 (131072 B), 16B-al

#define GLDS16(G, L) __builtin_amdgcn_global_load_lds(                    \
    (const __attribute__((address_space(1))) void*)(G),                   \
    (__attribute__((address_space(3))) void*)(L), 16, 0, 0)

// ---- prep: E' = -2E -> bf16 hi/lo A-frags, fused with esq ------------------
__global__ __launch_bounds__(512) void prep_kernel(
    const float* __restrict__ emb, unsigned short* __restrict__ ef,
    float* __restrict__ esq) {
  int idx  = blockIdx.x * 512 + threadIdx.x;   // 32768 = 512 codes * 64 d
  int code = idx >> 6, d = idx & 63;
  float s  = -2.0f * emb[code * 64 + d];
  unsigned u  = __float_as_uint(s);
  unsigned hi = (u + 0x7FFFu + ((u >> 16) & 1u)) >> 16;       // RNE bf16
  float lof   = s - __uint_as_float(hi << 16);
  unsigned v2 = __float_as_uint(lof);
  unsigned lo = (v2 + 0x7FFFu + ((v2 >> 16) & 1u)) >> 16;     // RNE bf16
  int tile = code >> 4, row = code & 15;
  int c = (d >> 5) & 1, g = (d >> 3) & 3, i = d & 7;
  int lane = row + (g << 4);
  size_t base = ((size_t)tile * 256 + (size_t)c * 128) * 8;
  ef[base + (size_t)(0 * 64 + lane) * 8 + i] = (unsigned short)hi;
  ef[base + (size_t)(1 * 64 + lane) * 8 + i] = (unsigned short)lo;
  // esq for this block's 8 codes (rows L1-hot from the reads above).
  if (threadIdx.x < 8) {
    int k = blockIdx.x * 8 + threadIdx.x;
    const float4* row4 = reinterpret_cast<const float4*>(emb + (size_t)k * D);
    float acc = 0.f;
#pragma unroll
    for (int j = 0; j < 16; ++j) {
      float4 v = row4[j];
      acc = fmaf(v.x, v.x, acc); acc = fmaf(v.y, v.y, acc);
      acc = fmaf(v.z, v.z, acc); acc = fmaf(v.w, v.w, acc);
    }
    esq[k] = acc;
  }
}

// RNE bf16 two-term split of 8 floats -> hi/lo bf16x8.
__device__ __forceinline__ void split8(float4 a, float4 b,
                                       bf16x8& h, bf16x8& lo) {
  float v[8] = {a.x, a.y, a.z, a.w, b.x, b.y, b.z, b.w};
#pragma unroll
  for (int i = 0; i < 8; ++i) {
    unsigned u  = __float_as_uint(v[i]);
    unsigned hi = (u + 0x7FFFu + ((u >> 16) & 1u)) >> 16;
    float lof   = v[i] - __uint_as_float(hi << 16);
    unsigned v2 = __float_as_uint(lof);
    unsigned l2 = (v2 + 0x7FFFu + ((v2 >> 16) & 1u)) >> 16;
    h[i]  = (short)hi;
    lo[i] = (short)l2;
  }
}

#define ARGMIN4(C, BASE, BEST, SECOND, BIDXV)               \
  {                                                         \
    _Pragma("unroll")                                       \
    for (int r = 0; r < 4; ++r) {                           \
      float v = (C)[r];                                     \
      bool lt = v < (BEST);                                 \
      float mn = fminf((SECOND), v);                        \
      (SECOND) = lt ? (BEST) : mn;                          \
      (BIDXV)  = lt ? ((BASE) + r) : (BIDXV);               \
      (BEST)   = lt ? v : (BEST);                           \
    }                                                       \
  }

// ---- kernel A: MFMA distances + inline rescan + fused epilogue -------------
__global__ __launch_bounds__(256) void vq_mfma(
    const float* __restrict__ z_e, const float* __restrict__ emb,
    const unsigned short* __restrict__ efrag, const float* __restrict__ esq_g,
    float* __restrict__ out_zq, float* __restrict__ out_idx,
    float* __restrict__ block_loss) {
  __shared__ float esql[K];                        // 2048 B
  __shared__ __align__(16) short lds_eb[2][4096];  // 2 x 8KB (tile-pair dbuf)
  __shared__ int   sIdx[128];
  __shared__ float wsm[4];

  const int t  = threadIdx.x;
  const int l  = t & 63;
  const int w  = t >> 6;
  const int wu = __builtin_amdgcn_readfirstlane(w);  // SGPR wave id
  const int g  = l >> 4, g4 = g << 2;
  const int gtok0 = blockIdx.x * 128;

  esql[t] = esq_g[t];
  esql[t + 256] = esq_g[t + 256];

  // z frags for two token rows, direct from global. RNE split = efrag's.
  bf16x8 zh0A, zl0A, zh1A, zl1A, zh0B, zl0B, zh1B, zl1B;
  {
    const int rowA = gtok0 + w * 32 + (l & 15);
    const float* zp = z_e + (size_t)rowA * D + g * 8;
    float4 q0 = *reinterpret_cast<const float4*>(zp);
    float4 q1 = *reinterpret_cast<const float4*>(zp + 4);
    float4 q2 = *reinterpret_cast<const float4*>(zp + 32);
    float4 q3 = *reinterpret_cast<const float4*>(zp + 36);
    split8(q0, q1, zh0A, zl0A);
    split8(q2, q3, zh1A, zl1A);
    zp += (size_t)16 * D;                          // rowB = rowA + 16
    q0 = *reinterpret_cast<const float4*>(zp);
    q1 = *reinterpret_cast<const float4*>(zp + 4);
    q2 = *reinterpret_cast<const float4*>(zp + 32);
    q3 = *reinterpret_cast<const float4*>(zp + 36);
    split8(q0, q1, zh0B, zl0B);
    split8(q2, q3, zh1B, zl1B);
  }

  const bf16x8* EF = reinterpret_cast<const bf16x8*>(efrag);
  GLDS16(EF + t,       &lds_eb[0][wu * 512]);
  GLDS16(EF + 256 + t, &lds_eb[0][2048 + wu * 512]);
  __syncthreads();

  float bestA = 3.402823466e38f, secondA = 3.402823466e38f;
  float bestB = 3.402823466e38f, secondB = 3.402823466e38f;
  int idxA = 0, idxB = 0;
  int buf = 0;

  for (int it = 0; it < 16; ++it) {
    if (it < 15) {                                 // stage next pair early
      const bf16x8* src = EF + (size_t)(it + 1) * 512;
      GLDS16(src + t,       &lds_eb[buf ^ 1][wu * 512]);
      GLDS16(src + 256 + t, &lds_eb[buf ^ 1][2048 + wu * 512]);
    }
    const bf16x8* eb = reinterpret_cast<const bf16x8*>(&lds_eb[buf][0]);

#pragma unroll
    for (int half = 0; half < 2; ++half) {
      const int tile = 2 * it + half;
      const bf16x8* tb = eb + half * 256;
      f32x4 CA = *reinterpret_cast<const f32x4*>(&esql[tile * 16 + g4]);
      f32x4 CB = CA;
      bf16x8 e0h = tb[l], e0l = tb[64 + l];
      bf16x8 e1h = tb[128 + l], e1l = tb[192 + l];
      __builtin_amdgcn_s_setprio(1);
      CA = __builtin_amdgcn_mfma_f32_16x16x32_bf16(e0h, zh0A, CA, 0, 0, 0);
      CB = __builtin_amdgcn_mfma_f32_16x16x32_bf16(e0h, zh0B, CB, 0, 0, 0);
      CA = __builtin_amdgcn_mfma_f32_16x16x32_bf16(e0h, zl0A, CA, 0, 0, 0);
      CB = __builtin_amdgcn_mfma_f32_16x16x32_bf16(e0h, zl0B, CB, 0, 0, 0);
      CA = __builtin_amdgcn_mfma_f32_16x16x32_bf16(e0l, zh0A, CA, 0, 0, 0);
      CB = __builtin_amdgcn_mfma_f32_16x16x32_bf16(e0l, zh0B, CB, 0, 0, 0);
      CA = __builtin_amdgcn_mfma_f32_16x16x32_bf16(e1h, zh1A, CA, 0, 0, 0);
      CB = __builtin_amdgcn_mfma_f32_16x16x32_bf16(e1h, zh1B, CB, 0, 0, 0);
      CA = __builtin_amdgcn_mfma_f32_16x16x32_bf16(e1h, zl1A, CA, 0, 0, 0);
      CB = __builtin_amdgcn_mfma_f32_16x16x32_bf16(e1h, zl1B, CB, 0, 0, 0);
      CA = __builtin_amdgcn_mfma_f32_16x16x32_bf16(e1l, zh1A, CA, 0, 0, 0);
      CB = __builtin_amdgcn_mfma_f32_16x16x32_bf16(e1l, zh1B, CB, 0, 0, 0);
      __builtin_amdgcn_s_setprio(0);

      const int base = tile * 16 + g4;             // ascending code order
      ARGMIN4(CA, base, bestA, secondA, idxA)
      ARGMIN4(CB, base, bestB, secondB, idxB)
    }
    __syncthreads();
    buf ^= 1;
  }

  // Reduce each group across lanes {l, l^16, l^32, l^48}; ties -> smaller code.
#pragma unroll
  for (int mask = 16; mask <= 32; mask <<= 1) {
    float ob, os; int oi; bool take; float hi2;
    ob = __shfl_xor(bestA, mask); oi = __shfl_xor(idxA, mask);
    os = __shfl_xor(secondA, mask);
    hi2 = fmaxf(bestA, ob);
    secondA = fminf(secondA, fminf(os, hi2));
    take = (ob < bestA) || (ob == bestA && oi < idxA);
    bestA = take ? ob : bestA; idxA = take ? oi : idxA;

    ob = __shfl_xor(bestB, mask); oi = __shfl_xor(idxB, mask);
    os = __shfl_xor(secondB, mask);
    hi2 = fmaxf(bestB, ob);
    secondB = fminf(secondB, fminf(os, hi2));
    take = (ob < bestB) || (ob == bestB && oi < idxB);
    bestB = take ? ob : bestB; idxB = take ? oi : idxB;
  }

  if (l < 16) {
    sIdx[w * 32 + l]      = idxA;
    sIdx[w * 32 + 16 + l] = idxB;
  }

  // Inline exact rescan of flagged tokens (wave-uniform ballot loop).
  {
    bool fA = (l < 16) && ((secondA - bestA) < THRESH);
    bool fB = (l < 16) && ((secondB - bestB) < THRESH);
    unsigned long long ba = __ballot(fA);
    unsigned long long bb = __ballot(fB);
    unsigned mask = (unsigned)((ba & 0xFFFFull) | ((bb & 0xFFFFull) << 16));
    while (mask) {
      const int j = __builtin_ctz(mask);
      mask &= mask - 1;
      const int n = gtok0 + w * 32 + j;
      const float4* zr = reinterpret_cast<const float4*>(z_e + (size_t)n * D);
      float acc[8];
#pragma unroll
      for (int m = 0; m < 8; ++m) acc[m] = 0.f;
#pragma unroll 4
      for (int i = 0; i < 16; ++i) {
        float4 z4 = zr[i];                         // uniform addr broadcast
#pragma unroll
        for (int m = 0; m < 8; ++m) {
          const float4 e4 = *reinterpret_cast<const float4*>(
              emb + (size_t)(l + 64 * m) * D + 4 * i);
          acc[m] = fmaf(z4.x, e4.x, acc[m]);
          acc[m] = fmaf(z4.y, e4.y, acc[m]);
          acc[m] = fmaf(z4.z, e4.z, acc[m]);
          acc[m] = fmaf(z4.w, e4.w, acc[m]);
        }
      }
      float best = 3.402823466e38f; int bid = 0;
#pragma unroll
      for (int m = 0; m < 8; ++m) {
        float s = fmaf(-2.f, acc[m], esq_g[l + 64 * m]);
        if (s < best) { best = s; bid = l + 64 * m; }
      }
#pragma unroll
      for (int mk = 1; mk <= 32; mk <<= 1) {       // lexicographic min
        float ob = __shfl_xor(best, mk);
        int   oi = __shfl_xor(bid, mk);
        bool take = (ob < best) || (ob == best && oi < bid);
        best = take ? ob : best;
        bid  = take ? oi : bid;
      }
      if (l == 0) sIdx[w * 32 + j] = bid;          // patch before epilogue
    }
  }
  __syncthreads();

  // Fused epilogue: 2 threads/token; gather + z_q_st + idx + loss.
  {
    const int tk = t >> 1, h = t & 1;
    const int n = gtok0 + tk;
    const int bi = sIdx[tk];
    const float4* er = reinterpret_cast<const float4*>(emb + (size_t)bi * D);
    const float4* zr = reinterpret_cast<const float4*>(z_e + (size_t)n * D);
    float4* orow = reinterpret_cast<float4*>(out_zq + (size_t)n * D);
    float lsum = 0.f;
#pragma unroll
    for (int j = 0; j < 8; ++j) {
      int i = h * 8 + j;
      float4 Q = er[i], Z = zr[i];
      float dx = Q.x - Z.x, dy = Q.y - Z.y, dz = Q.z - Z.z, dw = Q.w - Z.w;
      float4 st;
      st.x = Z.x + dx; st.y = Z.y + dy; st.z = Z.z + dz; st.w = Z.w + dw;
      orow[i] = st;
      lsum = fmaf(dx, dx, lsum); lsum = fmaf(dy, dy, lsum);
      lsum = fmaf(dz, dz, lsum); lsum = fmaf(dw, dw, lsum);
    }
    if (h == 0) out_idx[n] = (float)bi;
    float s = lsum;
#pragma unroll
    for (int off = 32; off > 0; off >>= 1) s += __shfl_xor(s, off, 64);
    if (l == 0) wsm[w] = s;
  }
  __syncthreads();
  if (t == 0) block_loss[blockIdx.x] = ((wsm[0] + wsm[1]) + wsm[2]) + wsm[3];
}

// ---- finalize loss (deterministic tree) ------------------------------------
__global__ __launch_bounds__(256) void loss_finalize(
    const float* __restrict__ bl, float* __restrict__ out_loss) {
  __shared__ float sm[256];
  const int t = threadIdx.x;
  float s = 0.f;
  for (int i = t; i < NBLK_A; i += 256) s += bl[i];
  sm[t] = s;
  __syncthreads();
#pragma unroll
  for (int off = 128; off > 0; off >>= 1) {
    if (t < off) sm[t] += sm[t + off];
    __syncthreads();
  }
  if (t == 0) out_loss[0] = sm[0] * (1.0f / 16777216.0f);  // /(N*D)
}

extern "C" void kernel_launch(void* const* d_in, const int* in_sizes, int n_in,
                              void* d_out, int out_size, void* d_ws, size_t ws_size,
                              hipStream_t stream) {
  const float* z_e = (const float*)d_in[0];
  const float* emb = (const float*)d_in[1];

  float* out      = (float*)d_out;
  float* out_zq   = out;                          // N*D
  float* out_idx  = out + (size_t)N_TOK * D;      // N
  float* out_loss = out_idx + N_TOK;              // 1

  char* wsb = (char*)d_ws;
  float*          esqp = (float*)(wsb + WS_ESQ);
  float*          bl   = (float*)(wsb + WS_BL);
  unsigned short* ef   = (unsigned short*)(wsb + WS_EFRAG);

  prep_kernel<<<64, 512, 0, stream>>>(emb, ef, esqp);
  vq_mfma<<<NBLK_A, 256, 0, stream>>>(z_e, emb, ef, esqp, out_zq, out_idx, bl);
  loss_finalize<<<1, 256, 0, stream>>>(bl, out_loss);
}